// Round 4
// baseline (945.639 us; speedup 1.0000x reference)
//
#include <hip/hip_runtime.h>
#include <hip/hip_cooperative_groups.h>

namespace cg = cooperative_groups;

// Problem constants (fixed instance): everything on device is float32.
#define NPL   16384        // nodes per level
#define DIM   64
#define CPN   8            // children per node
#define EPL   (NPL * CPN)  // edges per level block = 131072
#define NLEV  8

#define TPB    256
#define WAVES  4

// Cooperative (fused) config: 256 blocks = 1 block/CU -> 2x co-residency margin
#define CBLOCKS 256
#define C_NPB   (NPL / CBLOCKS)   // 64 nodes per block per level
#define C_NPW   (C_NPB / WAVES)   // 16 nodes per wave per level

// Fallback (per-level kernels) config
#define FBLOCKS 1024
#define F_NPB   (NPL / FBLOCKS)   // 16
#define F_NPW   (F_NPB / WAVES)   // 4

__device__ __forceinline__ void load_wrow(float* dst, const float* W, int row) {
    const float4* p = (const float4*)(W + row * DIM);   // 256B-aligned row
    #pragma unroll
    for (int q = 0; q < DIM / 4; ++q) {
        float4 v = p[q];
        dst[4*q+0] = v.x; dst[4*q+1] = v.y;
        dst[4*q+2] = v.z; dst[4*q+3] = v.w;
    }
}

// Process `nnodes` consecutive nodes of level `lvl` on one wave.
// Wave = node (sequentially); lane = output dim.
// out[g] = (lvl==0) ? x[g]·Wr_row : tanh(x[g]·Wr_row + agg·Wl_row + bl)
__device__ __forceinline__ void do_nodes(
    const float* __restrict__ x, const int* __restrict__ src,
    float* __restrict__ out,
    const float* wr, const float* wl, float bias,
    int lvl, int lane, int w, int pbase, int nnodes,
    float (*sX)[DIM], float (*sA)[DIM])
{
    const long gbase = (long)lvl * NPL;
    const int* ebase = src + (long)(lvl - 1) * EPL;

    // Prefetch node 0 (x row element + 8-child gather for this lane's dim).
    float xv  = x[(gbase + pbase) * DIM + lane];
    float agg = 0.0f;
    if (lvl > 0) {
        const int* ep = ebase + (long)pbase * CPN;
        #pragma unroll
        for (int j = 0; j < CPN; ++j)
            agg += out[(long)ep[j] * DIM + lane];   // coalesced 256B per wave
    }

    for (int c = 0; c < nnodes; ++c) {
        // Per-wave LDS broadcast slot; DS pipe is in-order within a wave,
        // so no barrier is needed (reads of node c precede writes of c+1).
        sX[w][lane] = xv;
        sA[w][lane] = agg;

        // Prefetch node c+1 while node c computes.
        if (c + 1 < nnodes) {
            const int p2 = pbase + c + 1;
            xv  = x[(gbase + p2) * DIM + lane];
            agg = 0.0f;
            if (lvl > 0) {
                const int* ep = ebase + (long)p2 * CPN;
                #pragma unroll
                for (int j = 0; j < CPN; ++j)
                    agg += out[(long)ep[j] * DIM + lane];
            }
        }

        // Dual GEMV, 4 interleaved accumulators (consecutive FMAs hit
        // different accs -> issue-bound, not FMA-latency-bound).
        float a0 = 0.f, a1 = 0.f, a2 = 0.f, a3 = (lvl > 0) ? bias : 0.f;
        const float4* A = (const float4*)sX[w];   // broadcast reads
        const float4* B = (const float4*)sA[w];
        #pragma unroll
        for (int k = 0; k < DIM / 4; ++k) {
            float4 av = A[k], bv = B[k];
            a0 += av.x * wr[4*k+0];
            a1 += av.y * wr[4*k+1];
            a2 += av.z * wr[4*k+2];
            a3 += av.w * wr[4*k+3];
            a0 += bv.x * wl[4*k+0];
            a1 += bv.y * wl[4*k+1];
            a2 += bv.z * wl[4*k+2];
            a3 += bv.w * wl[4*k+3];
        }
        float r = (a0 + a1) + (a2 + a3);
        if (lvl > 0) r = tanhf(r);
        out[(gbase + pbase + c) * DIM + lane] = r;
    }
}

// ---------------- Fused cooperative kernel (1 dispatch) ----------------
__global__ __launch_bounds__(TPB, 2) void dag_fused(
    const float* __restrict__ x, const int* __restrict__ src,
    const float* __restrict__ Wl, const float* __restrict__ bl,
    const float* __restrict__ Wr, float* __restrict__ out)
{
    __shared__ __align__(16) float sX[WAVES][DIM];
    __shared__ __align__(16) float sA[WAVES][DIM];

    const int lane = threadIdx.x & 63;
    const int w    = threadIdx.x >> 6;

    cg::grid_group grid = cg::this_grid();

    // Weights for this lane's output dim, held in VGPRs across all levels.
    float wr[DIM], wl[DIM];
    load_wrow(wr, Wr, lane);
    load_wrow(wl, Wl, lane);
    const float bias = bl[lane];

    const int pbase = blockIdx.x * C_NPB + w * C_NPW;

    for (int lvl = 0; lvl < NLEV; ++lvl) {
        do_nodes(x, src, out, wr, wl, bias, lvl, lane, w, pbase, C_NPW, sX, sA);
        // Level writes must be visible across XCDs before the next level's
        // gathers (per-XCD L2 non-coherent): release, grid barrier, acquire.
        __threadfence();
        grid.sync();
        __threadfence();
    }
}

// ---------------- Fallback: one normal kernel per level ----------------
__global__ __launch_bounds__(TPB) void dag_level(
    const float* __restrict__ x, const int* __restrict__ src,
    const float* __restrict__ Wl, const float* __restrict__ bl,
    const float* __restrict__ Wr, float* __restrict__ out, int lvl)
{
    __shared__ __align__(16) float sX[WAVES][DIM];
    __shared__ __align__(16) float sA[WAVES][DIM];

    const int lane = threadIdx.x & 63;
    const int w    = threadIdx.x >> 6;

    float wr[DIM], wl[DIM];
    load_wrow(wr, Wr, lane);
    load_wrow(wl, Wl, lane);
    const float bias = bl[lane];

    const int pbase = blockIdx.x * F_NPB + w * F_NPW;
    do_nodes(x, src, out, wr, wl, bias, lvl, lane, w, pbase, F_NPW, sX, sA);
}

extern "C" void kernel_launch(void* const* d_in, const int* in_sizes, int n_in,
                              void* d_out, int out_size, void* d_ws, size_t ws_size,
                              hipStream_t stream) {
    const float* x  = (const float*)d_in[0];   // [131072,64] f32
    const int*   ei = (const int*)d_in[1];     // [2, 917504] int32
    const float* Wl = (const float*)d_in[2];   // [64,64] f32
    const float* bl = (const float*)d_in[3];   // [64]    f32
    const float* Wr = (const float*)d_in[4];   // [64,64] f32
    float* out = (float*)d_out;                // [131072,64] f32

    const int* src = ei;                       // first E entries = src row

    void* args[] = {(void*)&x, (void*)&src, (void*)&Wl, (void*)&bl,
                    (void*)&Wr, (void*)&out};
    hipError_t e = hipLaunchCooperativeKernel((const void*)dag_fused,
                                              dim3(CBLOCKS), dim3(TPB),
                                              args, 0, stream);
    if (e != hipSuccess) {
        (void)hipGetLastError();               // clear sticky error
        // Proven-correct fallback: 8 dependent per-level launches.
        for (int lvl = 0; lvl < NLEV; ++lvl) {
            hipLaunchKernelGGL(dag_level, dim3(FBLOCKS), dim3(TPB), 0, stream,
                               x, src, Wl, bl, Wr, out, lvl);
        }
    }
}